// Round 1
// baseline (450.027 us; speedup 1.0000x reference)
//
#include <hip/hip_runtime.h>

#define TT 512
#define BB 32
#define CC 8000
#define NEGF (-1e30f)

// Gather lp_ext values: for each (t,b) read logit[t,b,{0,a1,a2}] and store
// in [t][k][b] layout so the DP kernel's per-step reads are coalesced.
__global__ void ctc_gather(const float* __restrict__ logit,
                           const int* __restrict__ targets,
                           float* __restrict__ lp) {
    int gid = blockIdx.x * blockDim.x + threadIdx.x;  // 0 .. T*B-1
    if (gid >= TT * BB) return;
    int b = gid & (BB - 1);
    int t = gid >> 5;
    int a1 = targets[2 * b];
    int a2 = targets[2 * b + 1];
    const float* row = logit + (size_t)gid * CC;  // gid == t*B + b
    float v0 = row[0];
    float v1 = row[a1];
    float v2 = row[a2];
    lp[(t * 3 + 0) * BB + b] = v0;
    lp[(t * 3 + 1) * BB + b] = v1;
    lp[(t * 3 + 2) * BB + b] = v2;
}

__device__ __forceinline__ float lse2(float x, float y) {
    float m = fmaxf(x, y);
    float d = fabsf(x - y);
    return m + log1pf(expf(-d));
}

__device__ __forceinline__ float lse3(float x, float y, float z) {
    float m = fmaxf(fmaxf(x, y), z);
    float s = expf(x - m) + expf(y - m) + expf(z - m);
    return m + logf(s);
}

// One wave; lane b runs the 5-state CTC forward recurrence for batch b.
__global__ void ctc_dp(const float* __restrict__ lp,
                       const int* __restrict__ targets,
                       float* __restrict__ out) {
    int tid = threadIdx.x;
    int b = (tid < BB) ? tid : 0;
    int a1 = targets[2 * b];
    int a2 = targets[2 * b + 1];
    // skip transition into state 3 (label a2) allowed iff a1 != a2
    float skipadd = (a1 != a2) ? 0.0f : NEGF;

    // t = 0 init: alpha[0] = lp(blank), alpha[1] = lp(a1)
    float A0 = lp[0 * BB + b];
    float A1 = lp[1 * BB + b];
    float A2 = NEGF, A3 = NEGF, A4 = NEGF;

    #pragma unroll 4
    for (int t = 1; t < TT; ++t) {
        const float* p = lp + t * 3 * BB;
        float l0 = p[b];           // blank
        float la = p[BB + b];      // label a1
        float lb = p[2 * BB + b];  // label a2
        float n0 = l0 + A0;
        float n1 = la + lse2(A1, A0);
        float n2 = l0 + lse2(A2, A1);
        float n3 = lb + lse3(A3, A2, A1 + skipadd);
        float n4 = l0 + lse2(A4, A3);
        A0 = n0; A1 = n1; A2 = n2; A3 = n3; A4 = n4;
    }

    float loglik = lse2(A3, A4);
    float loss = (tid < BB) ? (-0.5f * loglik) : 0.0f;  // -log_lik / L, L=2
    #pragma unroll
    for (int off = 32; off > 0; off >>= 1)
        loss += __shfl_down(loss, off, 64);
    if (tid == 0) out[0] = loss * (1.0f / BB);
}

extern "C" void kernel_launch(void* const* d_in, const int* in_sizes, int n_in,
                              void* d_out, int out_size, void* d_ws, size_t ws_size,
                              hipStream_t stream) {
    const float* logit   = (const float*)d_in[0];
    // d_in[1] (label) is unused by the reference
    const int*   targets = (const int*)d_in[2];
    float* lp  = (float*)d_ws;   // needs T*3*B*4 = 196608 bytes
    float* out = (float*)d_out;

    hipLaunchKernelGGL(ctc_gather, dim3((TT * BB + 255) / 256), dim3(256), 0, stream,
                       logit, targets, lp);
    hipLaunchKernelGGL(ctc_dp, dim3(1), dim3(64), 0, stream, lp, targets, out);
}

// Round 2
// 72.701 us; speedup vs baseline: 6.1901x; 6.1901x over previous
//
#include <hip/hip_runtime.h>

#define TT 512
#define BB 32
#define CC 8000
#define NEGF (-1e30f)
#define LOG2E 1.4426950408889634f
#define LN2   0.6931471805599453f

#if __has_builtin(__builtin_amdgcn_exp2f)
#define EXP2F(x) __builtin_amdgcn_exp2f(x)
#else
#define EXP2F(x) exp2f(x)
#endif
#if __has_builtin(__builtin_amdgcn_logf)
#define LOG2F(x) __builtin_amdgcn_logf(x)
#else
#define LOG2F(x) log2f(x)
#endif

// Gather the 3 needed log-probs per (t,b), pre-scaled to base-2 domain,
// into a [t][b][4] float4 workspace (one dwordx4 per DP step per lane).
__global__ void ctc_gather(const float* __restrict__ logit,
                           const int* __restrict__ targets,
                           float4* __restrict__ lp) {
    int gid = blockIdx.x * blockDim.x + threadIdx.x;  // 0 .. T*B-1, b fastest
    if (gid >= TT * BB) return;
    int b = gid & (BB - 1);
    int a1 = targets[2 * b];
    int a2 = targets[2 * b + 1];
    const float* row = logit + (size_t)gid * CC;  // gid == t*B + b
    float4 v;
    v.x = row[0]  * LOG2E;
    v.y = row[a1] * LOG2E;
    v.z = row[a2] * LOG2E;
    v.w = 0.0f;
    lp[gid] = v;
}

__device__ __forceinline__ float lse2_2(float x, float y) {
    float m = fmaxf(x, y);
    float d = fabsf(x - y);
    return m + LOG2F(1.0f + EXP2F(-d));
}

__device__ __forceinline__ float lse3_2(float x, float y, float z) {
    float m = fmaxf(fmaxf(x, y), z);
    float s = EXP2F(x - m) + EXP2F(y - m) + EXP2F(z - m);
    return m + LOG2F(s);
}

// One wave; lane b runs the 5-state CTC forward recurrence (base-2 domain).
__global__ void ctc_dp(const float4* __restrict__ lp,
                       const int* __restrict__ targets,
                       float* __restrict__ out) {
    int tid = threadIdx.x;
    int b = (tid < BB) ? tid : 0;
    int a1 = targets[2 * b];
    int a2 = targets[2 * b + 1];
    float skipadd = (a1 != a2) ? 0.0f : NEGF;

    float4 q0 = lp[b];  // t = 0
    float A0 = q0.x;
    float A1 = q0.y;
    float A2 = NEGF, A3 = NEGF, A4 = NEGF;

    #pragma unroll 8
    for (int t = 1; t < TT; ++t) {
        float4 q = lp[t * BB + b];
        float l0 = q.x;   // blank
        float la = q.y;   // label a1
        float lb = q.z;   // label a2
        float n0 = l0 + A0;
        float n1 = la + lse2_2(A1, A0);
        float n2 = l0 + lse2_2(A2, A1);
        float n3 = lb + lse3_2(A3, A2, A1 + skipadd);
        float n4 = l0 + lse2_2(A4, A3);
        A0 = n0; A1 = n1; A2 = n2; A3 = n3; A4 = n4;
    }

    float loglik2 = lse2_2(A3, A4);                       // base-2 log-lik
    float loss = (tid < BB) ? (-0.5f * LN2 * loglik2) : 0.0f;  // -loglik_e / L
    #pragma unroll
    for (int off = 32; off > 0; off >>= 1)
        loss += __shfl_down(loss, off, 64);
    if (tid == 0) out[0] = loss * (1.0f / BB);
}

extern "C" void kernel_launch(void* const* d_in, const int* in_sizes, int n_in,
                              void* d_out, int out_size, void* d_ws, size_t ws_size,
                              hipStream_t stream) {
    const float* logit   = (const float*)d_in[0];
    const int*   targets = (const int*)d_in[2];
    float4* lp  = (float4*)d_ws;   // T*B*16 = 256 KiB
    float*  out = (float*)d_out;

    hipLaunchKernelGGL(ctc_gather, dim3((TT * BB + 255) / 256), dim3(256), 0, stream,
                       logit, targets, lp);
    hipLaunchKernelGGL(ctc_dp, dim3(1), dim3(64), 0, stream, lp, targets, out);
}

// Round 3
// 35.686 us; speedup vs baseline: 12.6106x; 2.0372x over previous
//
#include <hip/hip_runtime.h>

#define TT 512
#define BB 32
#define CC 8000
#define NEGF (-1e30f)
#define LOG2E 1.4426950408889634f
#define LN2   0.6931471805599453f

#if __has_builtin(__builtin_amdgcn_exp2f)
#define EXP2F(x) __builtin_amdgcn_exp2f(x)
#else
#define EXP2F(x) exp2f(x)
#endif
#if __has_builtin(__builtin_amdgcn_logf)
#define LOG2F(x) __builtin_amdgcn_logf(x)   // v_log_f32 = log2
#else
#define LOG2F(x) log2f(x)
#endif

__device__ __forceinline__ float lse2_2(float x, float y) {
    float m = fmaxf(x, y);
    return m + LOG2F(EXP2F(x - m) + EXP2F(y - m));
}
__device__ __forceinline__ float lse3_2(float x, float y, float z) {
    float m = fmaxf(fmaxf(x, y), z);
    return m + LOG2F(EXP2F(x - m) + EXP2F(y - m) + EXP2F(z - m));
}
__device__ __forceinline__ float lse4_2(float x, float y, float z, float w) {
    float m = fmaxf(fmaxf(x, y), fmaxf(z, w));
    return m + LOG2F(EXP2F(x - m) + EXP2F(y - m) + EXP2F(z - m) + EXP2F(w - m));
}
__device__ __forceinline__ float lse5_2(float x, float y, float z, float w, float v) {
    float m = fmaxf(fmaxf(fmaxf(x, y), fmaxf(z, w)), v);
    return m + LOG2F(EXP2F(x - m) + EXP2F(y - m) + EXP2F(z - m) + EXP2F(w - m) + EXP2F(v - m));
}

// Phase A: one thread per (chunk c, batch b). Computes the upper-triangular
// 5x5 log-semiring product of the chunk's per-step transition matrices.
// Chunk 0 covers t=1..7 (7 steps); chunk c>=1 covers t=8c..8c+7 (8 steps).
// Output layout: ws[c*512 + e*32 + b], e = 0..14 packed upper-tri.
__global__ void ctc_chunks(const float* __restrict__ logit,
                           const int* __restrict__ targets,
                           float* __restrict__ ws) {
    int gid = blockIdx.x * 64 + threadIdx.x;   // 32 blocks x 64 = 2048
    int b = gid & 31;
    int c = gid >> 5;                          // 0..63
    int a1 = targets[2 * b];
    int a2 = targets[2 * b + 1];
    bool sk = (a1 != a2);
    float skipadd = sk ? 0.0f : NEGF;

    int tstart = 8 * c, nst = 8;
    if (c == 0) { tstart = 1; nst = 7; }

    // Load all step log-probs up front (base-2 scaled); loads are independent.
    float l0[8], la[8], lb[8];
    #pragma unroll
    for (int s = 0; s < 8; ++s) {
        const float* row = logit + (size_t)((tstart + s) * BB + b) * CC;
        l0[s] = row[0]  * LOG2E;
        la[s] = row[a1] * LOG2E;
        lb[s] = row[a2] * LOG2E;
    }

    // Init Acc = T_{tstart}. T[i][j] = lp[j] if i in pred(j) else NEG.
    // pred: 0<-{0}; 1<-{0,1}; 2<-{1,2}; 3<-{1(sk),2,3}; 4<-{3,4}
    float m00 = l0[0], m01 = la[0], m02 = NEGF, m03 = NEGF, m04 = NEGF;
    float m11 = la[0], m12 = l0[0], m13 = sk ? lb[0] : NEGF, m14 = NEGF;
    float m22 = l0[0], m23 = lb[0], m24 = NEGF;
    float m33 = lb[0], m34 = l0[0];
    float m44 = l0[0];

    #pragma unroll
    for (int s = 1; s < 8; ++s) {
        if (s >= nst) break;
        float p0 = l0[s], pa = la[s], pb = lb[s];
        float t00 = p0 + m00;
        float t01 = pa + lse2_2(m00, m01);
        float t02 = p0 + lse2_2(m01, m02);
        float t03 = pb + lse3_2(m01 + skipadd, m02, m03);
        float t04 = p0 + lse2_2(m03, m04);
        float t11 = pa + m11;
        float t12 = p0 + lse2_2(m11, m12);
        float t13 = pb + lse3_2(m11 + skipadd, m12, m13);
        float t14 = p0 + lse2_2(m13, m14);
        float t22 = p0 + m22;
        float t23 = pb + lse2_2(m22, m23);
        float t24 = p0 + lse2_2(m23, m24);
        float t33 = pb + m33;
        float t34 = p0 + lse2_2(m33, m34);
        float t44 = p0 + m44;
        m00 = t00; m01 = t01; m02 = t02; m03 = t03; m04 = t04;
        m11 = t11; m12 = t12; m13 = t13; m14 = t14;
        m22 = t22; m23 = t23; m24 = t24;
        m33 = t33; m34 = t34;
        m44 = t44;
    }

    float* w = ws + c * 512 + b;
    w[ 0 * 32] = m00; w[ 1 * 32] = m01; w[ 2 * 32] = m02; w[ 3 * 32] = m03;
    w[ 4 * 32] = m04; w[ 5 * 32] = m11; w[ 6 * 32] = m12; w[ 7 * 32] = m13;
    w[ 8 * 32] = m14; w[ 9 * 32] = m22; w[10 * 32] = m23; w[11 * 32] = m24;
    w[12 * 32] = m33; w[13 * 32] = m34; w[14 * 32] = m44;
}

#define LOADM(dst, base)                                                       \
    dst##00 = (base)[ 0 * 32]; dst##01 = (base)[ 1 * 32];                      \
    dst##02 = (base)[ 2 * 32]; dst##03 = (base)[ 3 * 32];                      \
    dst##04 = (base)[ 4 * 32]; dst##11 = (base)[ 5 * 32];                      \
    dst##12 = (base)[ 6 * 32]; dst##13 = (base)[ 7 * 32];                      \
    dst##14 = (base)[ 8 * 32]; dst##22 = (base)[ 9 * 32];                      \
    dst##23 = (base)[10 * 32]; dst##24 = (base)[11 * 32];                      \
    dst##33 = (base)[12 * 32]; dst##34 = (base)[13 * 32];                      \
    dst##44 = (base)[14 * 32]

// Phase B: one wave; lane b scans alpha through the 64 chunk matrices.
// Next chunk's matrix is prefetched into registers while composing current.
__global__ void ctc_scan(const float* __restrict__ ws,
                         const float* __restrict__ logit,
                         const int* __restrict__ targets,
                         float* __restrict__ out) {
    int tid = threadIdx.x;
    int b = (tid < BB) ? tid : 0;
    int a1 = targets[2 * b];

    // alpha at t=0
    const float* row0 = logit + (size_t)b * CC;
    float A0 = row0[0]  * LOG2E;
    float A1 = row0[a1] * LOG2E;
    float A2 = NEGF, A3 = NEGF, A4 = NEGF;

    float n00, n01, n02, n03, n04, n11, n12, n13, n14, n22, n23, n24, n33, n34, n44;
    float m00, m01, m02, m03, m04, m11, m12, m13, m14, m22, m23, m24, m33, m34, m44;
    const float* p = ws + b;
    LOADM(n, p);
    for (int c = 0; c < 64; ++c) {
        m00 = n00; m01 = n01; m02 = n02; m03 = n03; m04 = n04;
        m11 = n11; m12 = n12; m13 = n13; m14 = n14;
        m22 = n22; m23 = n23; m24 = n24;
        m33 = n33; m34 = n34; m44 = n44;
        const float* q = ws + (c + 1) * 512 + b;  // chunk 64 = pad, never used
        LOADM(n, q);
        float B0 = A0 + m00;
        float B1 = lse2_2(A0 + m01, A1 + m11);
        float B2 = lse3_2(A0 + m02, A1 + m12, A2 + m22);
        float B3 = lse4_2(A0 + m03, A1 + m13, A2 + m23, A3 + m33);
        float B4 = lse5_2(A0 + m04, A1 + m14, A2 + m24, A3 + m34, A4 + m44);
        A0 = B0; A1 = B1; A2 = B2; A3 = B3; A4 = B4;
    }

    float loglik2 = lse2_2(A3, A4);
    float loss = (tid < BB) ? (-0.5f * LN2 * loglik2) : 0.0f;  // -loglik_e / L
    #pragma unroll
    for (int off = 32; off > 0; off >>= 1)
        loss += __shfl_down(loss, off, 64);
    if (tid == 0) out[0] = loss * (1.0f / BB);
}

extern "C" void kernel_launch(void* const* d_in, const int* in_sizes, int n_in,
                              void* d_out, int out_size, void* d_ws, size_t ws_size,
                              hipStream_t stream) {
    const float* logit   = (const float*)d_in[0];
    const int*   targets = (const int*)d_in[2];
    float* ws  = (float*)d_ws;   // needs 65*512*4 = 133120 bytes
    float* out = (float*)d_out;

    hipLaunchKernelGGL(ctc_chunks, dim3(32), dim3(64), 0, stream,
                       logit, targets, ws);
    hipLaunchKernelGGL(ctc_scan, dim3(1), dim3(64), 0, stream,
                       ws, logit, targets, out);
}